// Round 5
// baseline (77.024 us; speedup 1.0000x reference)
//
#include <hip/hip_runtime.h>

#define N        384
#define DIM      256
#define D4       (DIM / 4)       // 64 float4 per row
#define CHUNK_K4 8               // k4 staged per chunk
#define NCHUNK   4               // chunks per k-half: 4*8 = 32 k4
#define MARGIN_F 0.2f
#define NANCH    2               // anchors per block
#define NBLK     (N / NANCH)     // 192 blocks
#define NTHR     (2 * N)         // 768 threads: split-K x2 over 384 columns
#define NWAVE    (NTHR / 64)     // 12 waves
#define MAXPOS   64              // labels ~ Binom(384,1/32): mean 12; >14 sigma

// ---------------------------------------------------------------------------
// r4 skeleton (single fused kernel, split-K x2, thread-per-column, analytic
// normalization) with the two biggest LDS consumers removed:
//
//  1) anchors are NOT staged/read through LDS: the inner loop dots against the
//     RAW anchor rows via uniform (blockIdx-only) global addresses -> s_load
//     into SGPRs; FMA takes the anchor as its one allowed SGPR operand.
//     (r4 spent ~3.8us/CU of ds_read_b128 cycles broadcasting these.)
//  2) staging uses __builtin_amdgcn_global_load_lds (16B): no ds_write, no
//     VGPR round-trip. LDS dest is linear-in-lane (HW requirement), so the
//     old +1 pad is replaced by an XOR swizzle j^(row&7) applied to the
//     SOURCE address; the column ds_read_b128 applies the same involution and
//     stays at the 8-way b128 bank floor. Read order ascends in GLOBAL k ->
//     accumulation order (and thus all fp results) bit-identical to r4.
//
// Workspace: 16 bytes (sum, cnt, done) zeroed by the tiny memset.
// ---------------------------------------------------------------------------

__device__ __forceinline__ void dma16(const float4* g, float4* l) {
    __builtin_amdgcn_global_load_lds(
        (const __attribute__((address_space(1))) void*)g,
        (__attribute__((address_space(3))) void*)l, 16, 0, 0);
}

__global__ __launch_bounds__(NTHR) void triplet_kernel(
    const float4* __restrict__ emb4, const int* __restrict__ labels,
    float* __restrict__ accum_sum, unsigned int* __restrict__ accum_cnt,
    unsigned int* __restrict__ done_cnt, float* __restrict__ out)
{
    const int i0   = blockIdx.x * NANCH;
    const int tid  = threadIdx.x;          // 0..767
    const int wave = tid >> 6, lane = tid & 63;
    const int kgrp = (tid >= N) ? 1 : 0;   // which k-half this thread sums
    const int col  = tid - kgrp * N;       // 0..383: column owned

    __shared__ float4 ebuf[2][N][CHUNK_K4];  // 96 KB, unpadded (XOR-swizzled)
    __shared__ float  pacc[3][N];            // vv, rd0, rd1 partials from kgrp1
    __shared__ float  Drow[NANCH][N];        // distance rows
    __shared__ float  invA[NANCH], sqA[NANCH];
    __shared__ int    lab[N];
    __shared__ int    posList[NANCH][MAXPOS];
    __shared__ int    posCnt[NANCH];
    __shared__ float        sredS[NWAVE];
    __shared__ unsigned int sredC[NWAVE];

    if (tid < N) lab[tid] = labels[tid];
    if (tid < NANCH) posCnt[tid] = 0;

    // raw anchor rows; all addresses blockIdx-only -> scalar loads
    const float4* __restrict__ arow0 = emb4 + (size_t)i0 * D4;
    const float4* __restrict__ arow1 = arow0 + D4;

    // ---- staged dot loop: DMA chunk -> barrier -> dot -> barrier
    float vv = 0.0f, rd0 = 0.0f, rd1 = 0.0f;
    const int kbase = kgrp * (NCHUNK * CHUNK_K4);    // 0 or 32
    const int wbase = col & ~63;                     // wave-uniform slot base

    for (int c = 0; c < NCHUNK; ++c) {
        const int kk0 = kbase + c * CHUNK_K4;
        // stage: 3072 slots per kgrp, 8 per thread; LDS dest linear in lane,
        // source pre-swizzled so slot (row, js) holds element (row, js^(row&7))
        #pragma unroll
        for (int i = 0; i < 8; ++i) {
            const int slot = i * N + col;            // lane-consecutive
            const int row  = slot >> 3, js = slot & 7;
            const int jg   = js ^ (row & 7);
            dma16(&emb4[row * D4 + kk0 + jg],
                  &ebuf[kgrp][0][0] + (i * N + wbase));   // wave-uniform base
        }
        __syncthreads();                             // drains vmcnt, barrier

        #pragma unroll
        for (int j = 0; j < CHUNK_K4; ++j) {         // global-k ascending order
            const float4 v  = ebuf[kgrp][col][j ^ (col & 7)];  // 8-way floor
            const float4 a0 = arow0[kk0 + j];        // uniform -> SGPR
            const float4 a1 = arow1[kk0 + j];
            vv  += v.x*v.x  + v.y*v.y  + v.z*v.z  + v.w*v.w;
            rd0 += v.x*a0.x + v.y*a0.y + v.z*a0.z + v.w*a0.w;
            rd1 += v.x*a1.x + v.y*a1.y + v.z*a1.z + v.w*a1.w;
        }
        __syncthreads();                             // before overwrite
    }

    // ---- combine k-halves, publish anchor inv/sq; kgrp1 builds pos lists
    if (kgrp == 1) { pacc[0][col] = vv; pacc[1][col] = rd0; pacc[2][col] = rd1; }
    __syncthreads();

    float inv_j = 0.0f, sq_j = 0.0f;
    if (kgrp == 0) {
        vv  += pacc[0][col];
        rd0 += pacc[1][col];
        rd1 += pacc[2][col];
        inv_j = 1.0f / fmaxf(sqrtf(vv), 1e-12f);
        sq_j  = vv * inv_j * inv_j;         // = ref's sum(e_norm^2) for row j
        if (col == i0)     { invA[0] = inv_j; sqA[0] = sq_j; }
        if (col == i0 + 1) { invA[1] = inv_j; sqA[1] = sq_j; }
    } else {
        const int lj = lab[col];
        #pragma unroll
        for (int a = 0; a < NANCH; ++a) {
            const int ia = i0 + a;
            if (lj == lab[ia] && col != ia)
                posList[a][atomicAdd(&posCnt[a], 1)] = col;
        }
    }
    __syncthreads();

    if (kgrp == 0) {                        // finalize distance rows
        float d2 = fmaxf(sqA[0] + sq_j - 2.0f * (rd0 * (invA[0] * inv_j)), 0.0f);
        Drow[0][col] = (d2 > 0.0f) ? sqrtf(d2) : 0.0f;  // ref: sqrt(where(pos,d2,1))*pos
        d2       = fmaxf(sqA[1] + sq_j - 2.0f * (rd1 * (invA[1] * inv_j)), 0.0f);
        Drow[1][col] = (d2 > 0.0f) ? sqrtf(d2) : 0.0f;
    }
    __syncthreads();

    // ---- semihard accumulation; thread owns (negative = col, anchor = kgrp)
    float        lsum = 0.0f;
    unsigned int lcnt = 0u;
    {
        const int a  = kgrp;
        const int li = lab[i0 + a];
        if (lab[col] != li) {
            const float dk = Drow[a][col];     // an
            const int   np = posCnt[a];        // ~11 positives
            for (int p = 0; p < np; ++p) {
                const float tm = dk - Drow[a][posList[a][p]];   // an - ap
                if (tm > 0.0f && tm <= MARGIN_F) {
                    const float l = MARGIN_F - tm;              // max(MARGIN-tm,0)
                    lsum += l;
                    if (l > 0.0f) lcnt++;                       // strict losses>0
                }
            }
        }
    }

    // ---- block reduce, device accumulate, last-block finalize
    #pragma unroll
    for (int off = 32; off > 0; off >>= 1) {
        lsum += __shfl_down(lsum, off, 64);
        lcnt += __shfl_down(lcnt, off, 64);
    }
    if (lane == 0) { sredS[wave] = lsum; sredC[wave] = lcnt; }
    __syncthreads();

    if (tid == 0) {
        float        S = 0.0f;
        unsigned int C = 0u;
        #pragma unroll
        for (int w = 0; w < NWAVE; ++w) { S += sredS[w]; C += sredC[w]; }
        if (S != 0.0f || C != 0u) {
            atomicAdd(accum_sum, S);
            atomicAdd(accum_cnt, C);
        }
        __threadfence();                        // order adds before done++
        const unsigned int prev = atomicAdd(done_cnt, 1);
        if (prev == NBLK - 1) {                 // last block computes the mean
            const float        Sall = atomicAdd(accum_sum, 0.0f);
            const unsigned int Call = atomicAdd(accum_cnt, 0u);
            out[0] = (Call > 0u) ? (Sall / (float)Call) : 0.0f;
        }
    }
}

extern "C" void kernel_launch(void* const* d_in, const int* in_sizes, int n_in,
                              void* d_out, int out_size, void* d_ws, size_t ws_size,
                              hipStream_t stream) {
    const float4* emb4   = (const float4*)d_in[0];   // (384, 256) fp32
    const int*    labels = (const int*)d_in[1];      // (384,) int32
    float*        out    = (float*)d_out;            // scalar fp32

    float*        accum_sum = (float*)d_ws;                    // [0]
    unsigned int* accum_cnt = (unsigned int*)accum_sum + 1;    // [1]
    unsigned int* done_cnt  = (unsigned int*)accum_sum + 2;    // [2]

    hipMemsetAsync(d_ws, 0, 16, stream);           // zero sum/cnt/done (graph-legal)
    triplet_kernel<<<NBLK, NTHR, 0, stream>>>(emb4, labels,
                                              accum_sum, accum_cnt, done_cnt, out);
}